// Round 1
// baseline (1414.136 us; speedup 1.0000x reference)
//
#include <hip/hip_runtime.h>
#include <math.h>

// ---------- helpers ----------
__device__ __forceinline__ unsigned fkey(float x) {
    unsigned b = __float_as_uint(x);
    return (b & 0x80000000u) ? ~b : (b | 0x80000000u);
}
__device__ __forceinline__ float finv(unsigned k) {
    return __uint_as_float((k & 0x80000000u) ? (k & 0x7fffffffu) : ~k);
}
__device__ __forceinline__ float lrelu(float v) { return v > 0.f ? v : 0.2f * v; }

// ---------- kernels ----------

// deg[dst] += ew  (real edges only; self-loop +1 folded into k_dis)
__global__ void k_deg(const int* __restrict__ dst, const float* __restrict__ ew,
                      float* __restrict__ deg, int E) {
    int e = blockIdx.x * 256 + threadIdx.x;
    if (e < E) atomicAdd(&deg[dst[e]], ew[e]);
}

// dis = rsqrt(deg + 1)
__global__ void k_dis(float* __restrict__ d, int N) {
    int n = blockIdx.x * 256 + threadIdx.x;
    if (n < N) d[n] = rsqrtf(d[n] + 1.0f);
}

// xw = X @ W1   (N x 128) @ (128 x 64)
__global__ __launch_bounds__(256) void k_gemm1(const float* __restrict__ X,
                                               const float* __restrict__ W1,
                                               float* __restrict__ xw, int N) {
    __shared__ __align__(16) float Ws[128 * 64];
    __shared__ __align__(16) float Xs[32][129];
    int tid = threadIdx.x;
    int m0 = blockIdx.x * 32;
    const float4* W4 = (const float4*)W1;
    float4* Ws4 = (float4*)Ws;
#pragma unroll
    for (int i = 0; i < 8; i++) Ws4[tid + i * 256] = W4[tid + i * 256];
#pragma unroll
    for (int i = 0; i < 4; i++) {
        int idx = tid + i * 256;   // float4 index in 32x128 tile
        int r = idx >> 5;          // 32 float4 per row
        int c = idx & 31;
        float4 v = ((const float4*)(X + (size_t)(m0 + r) * 128))[c];
        Xs[r][c * 4 + 0] = v.x; Xs[r][c * 4 + 1] = v.y;
        Xs[r][c * 4 + 2] = v.z; Xs[r][c * 4 + 3] = v.w;
    }
    __syncthreads();
    int r = tid & 31;
    int c0 = (tid >> 5) * 8;
    float acc[8] = {0, 0, 0, 0, 0, 0, 0, 0};
#pragma unroll 4
    for (int k = 0; k < 128; k++) {
        float xv = Xs[r][k];
        const float4* wr = (const float4*)&Ws[k * 64 + c0];
        float4 w0 = wr[0], w1 = wr[1];
        acc[0] += xv * w0.x; acc[1] += xv * w0.y; acc[2] += xv * w0.z; acc[3] += xv * w0.w;
        acc[4] += xv * w1.x; acc[5] += xv * w1.y; acc[6] += xv * w1.z; acc[7] += xv * w1.w;
    }
    float* out = xw + (size_t)(m0 + r) * 64 + c0;
    ((float4*)out)[0] = make_float4(acc[0], acc[1], acc[2], acc[3]);
    ((float4*)out)[1] = make_float4(acc[4], acc[5], acc[6], acc[7]);
}

// x[dst] += xw[src] * norm   over Et edges (virtual self-loops e>=E)
__global__ __launch_bounds__(256) void k_scatter(const int* __restrict__ src,
                                                 const int* __restrict__ dst,
                                                 const float* __restrict__ ew,
                                                 const float* __restrict__ dis,
                                                 const float* __restrict__ xw,
                                                 float* __restrict__ x, int E, int Et) {
    int lane = threadIdx.x & 63;
    int w = threadIdx.x >> 6;
    long long gw = (long long)blockIdx.x * 4 + w;
    long long stride = (long long)gridDim.x * 4;
    for (long long base = gw * 64; base < Et; base += stride * 64) {
        int e = (int)base + lane;
        float nrm = 0.f; int s = 0, d = 0;
        if (e < Et) {
            float wgt;
            if (e < E) { s = src[e]; d = dst[e]; wgt = ew[e]; }
            else       { s = d = e - E; wgt = 1.f; }
            nrm = dis[s] * wgt * dis[d];
        }
        if (base + 64 <= Et) {
#pragma unroll 8
            for (int i = 0; i < 64; i++) {
                float nn = __shfl(nrm, i);
                int ss = __shfl(s, i);
                int dd = __shfl(d, i);
                atomicAdd(&x[(size_t)dd * 64 + lane], nn * xw[(size_t)ss * 64 + lane]);
            }
        } else {
            int cnt = (int)(Et - base);
            for (int i = 0; i < cnt; i++) {
                float nn = __shfl(nrm, i);
                int ss = __shfl(s, i);
                int dd = __shfl(d, i);
                atomicAdd(&x[(size_t)dd * 64 + lane], nn * xw[(size_t)ss * 64 + lane]);
            }
        }
    }
}

// g = relu(x + b1) @ W2   (N x 64) @ (64 x 192)
__global__ __launch_bounds__(256) void k_gemm2(const float* __restrict__ x,
                                               const float* __restrict__ W2,
                                               const float* __restrict__ b1,
                                               float* __restrict__ g, int N) {
    __shared__ __align__(16) float Ws[64 * 192];
    __shared__ __align__(16) float Xs[32][65];
    __shared__ float b1s[64];
    int tid = threadIdx.x;
    int m0 = blockIdx.x * 32;
    if (tid < 64) b1s[tid] = b1[tid];
    __syncthreads();
    const float4* W4 = (const float4*)W2;
    float4* Ws4 = (float4*)Ws;
#pragma unroll
    for (int i = 0; i < 12; i++) Ws4[tid + i * 256] = W4[tid + i * 256];
#pragma unroll
    for (int i = 0; i < 2; i++) {
        int idx = tid + i * 256;   // float4 index in 32x64 tile
        int r = idx >> 4;          // 16 float4 per row
        int c4 = idx & 15;
        float4 v = ((const float4*)(x + (size_t)(m0 + r) * 64))[c4];
        v.x = fmaxf(v.x + b1s[c4 * 4 + 0], 0.f);
        v.y = fmaxf(v.y + b1s[c4 * 4 + 1], 0.f);
        v.z = fmaxf(v.z + b1s[c4 * 4 + 2], 0.f);
        v.w = fmaxf(v.w + b1s[c4 * 4 + 3], 0.f);
        Xs[r][c4 * 4 + 0] = v.x; Xs[r][c4 * 4 + 1] = v.y;
        Xs[r][c4 * 4 + 2] = v.z; Xs[r][c4 * 4 + 3] = v.w;
    }
    __syncthreads();
    int r = tid & 31;
    int c0 = (tid >> 5) * 24;
    float acc[24];
#pragma unroll
    for (int j = 0; j < 24; j++) acc[j] = 0.f;
#pragma unroll 4
    for (int k = 0; k < 64; k++) {
        float xv = Xs[r][k];
        const float4* wr = (const float4*)&Ws[k * 192 + c0];
#pragma unroll
        for (int q = 0; q < 6; q++) {
            float4 wv = wr[q];
            acc[q * 4 + 0] += xv * wv.x;
            acc[q * 4 + 1] += xv * wv.y;
            acc[q * 4 + 2] += xv * wv.z;
            acc[q * 4 + 3] += xv * wv.w;
        }
    }
    float* out = g + (size_t)(m0 + r) * 192 + c0;
#pragma unroll
    for (int q = 0; q < 6; q++)
        ((float4*)out)[q] = make_float4(acc[q * 4 + 0], acc[q * 4 + 1], acc[q * 4 + 2], acc[q * 4 + 3]);
}

// a_src[n,h] = <g[n,h,:], att_src[h,:]> ; a_dst likewise
__global__ __launch_bounds__(256) void k_att(const float* __restrict__ g,
                                             const float* __restrict__ att_src,
                                             const float* __restrict__ att_dst,
                                             float* __restrict__ asrc,
                                             float* __restrict__ adst, int N3) {
    __shared__ float as_s[192], ad_s[192];
    int tid = threadIdx.x;
    if (tid < 192) { as_s[tid] = att_src[tid]; ad_s[tid] = att_dst[tid]; }
    __syncthreads();
    int idx = blockIdx.x * 256 + tid;   // idx = n*3+h
    if (idx < N3) {
        int n = idx / 3, h = idx - 3 * n;
        const float4* gr = (const float4*)(g + (size_t)n * 192 + h * 64);
        const float4* av = (const float4*)(as_s + h * 64);
        const float4* bv = (const float4*)(ad_s + h * 64);
        float sa = 0.f, sb = 0.f;
#pragma unroll
        for (int i = 0; i < 16; i++) {
            float4 gv = gr[i]; float4 a = av[i]; float4 b = bv[i];
            sa += gv.x * a.x + gv.y * a.y + gv.z * a.z + gv.w * a.w;
            sb += gv.x * b.x + gv.y * b.y + gv.z * b.z + gv.w * b.w;
        }
        asrc[idx] = sa; adst[idx] = sb;
    }
}

// segment max of alpha over dst (order-preserving uint keys, 0 == -inf sentinel)
__global__ void ke1(const int* __restrict__ src, const int* __restrict__ dst,
                    const float* __restrict__ asrc, const float* __restrict__ adst,
                    unsigned* __restrict__ amaxk, int E, int Et) {
    int e = blockIdx.x * 256 + threadIdx.x;
    if (e >= Et) return;
    int s, d;
    if (e < E) { s = src[e]; d = dst[e]; } else { s = d = e - E; }
#pragma unroll
    for (int h = 0; h < 3; h++) {
        float al = lrelu(asrc[s * 3 + h] + adst[d * 3 + h]);
        atomicMax(&amaxk[d * 3 + h], fkey(al));
    }
}

// denom[dst] += exp(alpha - amax[dst])
__global__ void ke2(const int* __restrict__ src, const int* __restrict__ dst,
                    const float* __restrict__ asrc, const float* __restrict__ adst,
                    const unsigned* __restrict__ amaxk, float* __restrict__ denom,
                    int E, int Et) {
    int e = blockIdx.x * 256 + threadIdx.x;
    if (e >= Et) return;
    int s, d;
    if (e < E) { s = src[e]; d = dst[e]; } else { s = d = e - E; }
#pragma unroll
    for (int h = 0; h < 3; h++) {
        float al = lrelu(asrc[s * 3 + h] + adst[d * 3 + h]);
        float ex = __expf(al - finv(amaxk[d * 3 + h]));
        atomicAdd(&denom[d * 3 + h], ex);
    }
}

// gsum[h*64+f] += sum_e attn(e,h) * g[src(e), h*64+f]
// block = 192 threads = 3 waves; wave w handles head w, lane = feature
__global__ __launch_bounds__(192) void ke3(const int* __restrict__ src,
                                           const int* __restrict__ dst,
                                           const float* __restrict__ asrc,
                                           const float* __restrict__ adst,
                                           const unsigned* __restrict__ amaxk,
                                           const float* __restrict__ denom,
                                           const float* __restrict__ g,
                                           float* __restrict__ gsum, int E, int Et) {
    int lane = threadIdx.x & 63;
    int h = threadIdx.x >> 6;
    float acc = 0.f;
    for (long long base = (long long)blockIdx.x * 64; base < Et;
         base += (long long)gridDim.x * 64) {
        int e = (int)base + lane;
        float attn = 0.f; int s = 0;
        if (e < Et) {
            int d;
            if (e < E) { s = src[e]; d = dst[e]; } else { s = d = e - E; }
            float al = lrelu(asrc[s * 3 + h] + adst[d * 3 + h]);
            float mx = finv(amaxk[d * 3 + h]);
            attn = __expf(al - mx) / (denom[d * 3 + h] + 1e-16f);
        }
        if (base + 64 <= Et) {
#pragma unroll 8
            for (int i = 0; i < 64; i++) {
                float a = __shfl(attn, i);
                int ss = __shfl(s, i);
                acc += a * g[(size_t)ss * 192 + h * 64 + lane];
            }
        } else {
            int cnt = (int)(Et - base);
            for (int i = 0; i < cnt; i++) {
                float a = __shfl(attn, i);
                int ss = __shfl(s, i);
                acc += a * g[(size_t)ss * 192 + h * 64 + lane];
            }
        }
    }
    atomicAdd(&gsum[h * 64 + lane], acc);
}

// out = gsum/N + b2
__global__ void k_final(const float* __restrict__ gsum, const float* __restrict__ b2,
                        float* __restrict__ out, float invN) {
    int j = threadIdx.x;
    if (j < 192) out[j] = gsum[j] * invN + b2[j];
}

// ---------- launcher ----------
extern "C" void kernel_launch(void* const* d_in, const int* in_sizes, int n_in,
                              void* d_out, int out_size, void* d_ws, size_t ws_size,
                              hipStream_t stream) {
    const float* X   = (const float*)d_in[0];
    const int*   ei  = (const int*)d_in[1];
    const float* ew  = (const float*)d_in[2];
    const float* W1  = (const float*)d_in[3];
    const float* b1  = (const float*)d_in[4];
    const float* W2  = (const float*)d_in[5];
    const float* b2  = (const float*)d_in[6];
    const float* ats = (const float*)d_in[7];
    const float* atd = (const float*)d_in[8];

    int N  = in_sizes[0] / 128;
    int E  = in_sizes[1] / 2;
    int Et = E + N;
    const int* srcI = ei;
    const int* dstI = ei + E;

    float* ws = (float*)d_ws;
    float* xw    = ws;                        // N*64
    float* g     = ws + (size_t)N * 64;       // N*192
    float* x     = ws + (size_t)N * 256;      // N*64   (zeroed)
    float* dis   = ws + (size_t)N * 320;      // N      (deg -> dis, zeroed)
    float* asrc  = ws + (size_t)N * 321;      // N*3
    float* adst  = ws + (size_t)N * 324;      // N*3
    unsigned* amaxk = (unsigned*)(ws + (size_t)N * 327); // N*3 (zeroed)
    float* denom = ws + (size_t)N * 330;      // N*3   (zeroed)
    float* gsum  = ws + (size_t)N * 333;      // 192   (zeroed)

    // zero everything from x through gsum in one memset
    size_t zbytes = ((size_t)N * 77 + 192) * sizeof(float);
    hipMemsetAsync(x, 0, zbytes, stream);

    k_deg<<<(E + 255) / 256, 256, 0, stream>>>(dstI, ew, dis, E);
    k_dis<<<(N + 255) / 256, 256, 0, stream>>>(dis, N);
    k_gemm1<<<N / 32, 256, 0, stream>>>(X, W1, xw, N);
    k_scatter<<<832, 256, 0, stream>>>(srcI, dstI, ew, dis, xw, x, E, Et);
    k_gemm2<<<N / 32, 256, 0, stream>>>(x, W2, b1, g, N);
    k_att<<<(3 * N + 255) / 256, 256, 0, stream>>>(g, ats, atd, asrc, adst, 3 * N);
    ke1<<<(Et + 255) / 256, 256, 0, stream>>>(srcI, dstI, asrc, adst, amaxk, E, Et);
    ke2<<<(Et + 255) / 256, 256, 0, stream>>>(srcI, dstI, asrc, adst, amaxk, denom, E, Et);
    ke3<<<1664, 192, 0, stream>>>(srcI, dstI, asrc, adst, amaxk, denom, g, gsum, E, Et);
    k_final<<<1, 192, 0, stream>>>(gsum, b2, (float*)d_out, 1.0f / (float)N);
}

// Round 2
// 906.411 us; speedup vs baseline: 1.5601x; 1.5601x over previous
//
#include <hip/hip_runtime.h>
#include <math.h>

__device__ __forceinline__ float lrelu(float v) { return v > 0.f ? v : 0.2f * v; }

__device__ __forceinline__ float wave_max(float v) {
#pragma unroll
    for (int o = 32; o > 0; o >>= 1) v = fmaxf(v, __shfl_xor(v, o));
    return v;
}

// ---------- CSR build ----------

// cnt[dst]++ for real edges (self-loop +1 folded into scan)
__global__ void k_hist(const int* __restrict__ dst, int* __restrict__ cnt, int E) {
    int e = blockIdx.x * 256 + threadIdx.x;
    if (e < E) atomicAdd(&cnt[dst[e]], 1);
}

// block-local exclusive scan of (cnt[n]+1), 1024 elems/block
__global__ __launch_bounds__(256) void k_scan1(const int* __restrict__ cnt,
                                               int* __restrict__ off,
                                               int* __restrict__ partials, int N) {
    __shared__ int sh[256];
    int tid = threadIdx.x;
    int base = blockIdx.x * 1024 + tid * 4;
    int v[4]; int tsum = 0;
#pragma unroll
    for (int i = 0; i < 4; i++) {
        int n = base + i;
        int c = (n < N) ? cnt[n] + 1 : 0;
        v[i] = tsum; tsum += c;
    }
    sh[tid] = tsum; __syncthreads();
    int mine = tsum;
    for (int o = 1; o < 256; o <<= 1) {
        int t = (tid >= o) ? sh[tid - o] : 0;
        __syncthreads();
        sh[tid] += t;
        __syncthreads();
    }
    int excl = sh[tid] - mine;
#pragma unroll
    for (int i = 0; i < 4; i++) {
        int n = base + i;
        if (n < N) off[n] = excl + v[i];
    }
    if (tid == 255) partials[blockIdx.x] = sh[255];
}

// exclusive scan of block partials (nb <= 256)
__global__ void k_scan2(int* __restrict__ partials, int nb) {
    __shared__ int sh[256];
    int tid = threadIdx.x;
    int v = (tid < nb) ? partials[tid] : 0;
    sh[tid] = v; __syncthreads();
    for (int o = 1; o < 256; o <<= 1) {
        int t = (tid >= o) ? sh[tid - o] : 0;
        __syncthreads();
        sh[tid] += t;
        __syncthreads();
    }
    if (tid < nb) partials[tid] = sh[tid] - v;
}

// add partial prefix; duplicate into cursor
__global__ void k_scan3(int* __restrict__ off, int* __restrict__ cursor,
                        const int* __restrict__ partials, int N, int Et) {
    int base = blockIdx.x * 1024 + threadIdx.x * 4;
    int add = partials[blockIdx.x];
#pragma unroll
    for (int i = 0; i < 4; i++) {
        int n = base + i;
        if (n < N) { int o = off[n] + add; off[n] = o; cursor[n] = o; }
    }
    if (blockIdx.x == 0 && threadIdx.x == 0) { off[N] = Et; cursor[N] = Et; }
}

// scatter edges (and virtual self-loops) into dst-sorted packed array
__global__ void k_fill(const int* __restrict__ src, const int* __restrict__ dst,
                       const float* __restrict__ ew, int* __restrict__ cursor,
                       unsigned long long* __restrict__ epk, int E, int Et) {
    int e = blockIdx.x * 256 + threadIdx.x;
    if (e >= Et) return;
    int s, d; float w;
    if (e < E) { s = src[e]; d = dst[e]; w = ew[e]; }
    else       { s = d = e - E; w = 1.0f; }
    int p = atomicAdd(&cursor[d], 1);
    epk[p] = ((unsigned long long)__float_as_uint(w) << 32) | (unsigned)s;
}

// dis[n] = rsqrt(sum of edge weights incl. self-loop)
__global__ void k_degdis(const int* __restrict__ off,
                         const unsigned long long* __restrict__ epk,
                         float* __restrict__ dis, int N) {
    int n = blockIdx.x * 256 + threadIdx.x;
    if (n >= N) return;
    int b = off[n], e2 = off[n + 1];
    float s = 0.f;
    for (int i = b; i < e2; i++) s += __uint_as_float((unsigned)(epk[i] >> 32));
    dis[n] = rsqrtf(s);
}

// ---------- dense kernels ----------

// xw = X @ W1   (N x 128) @ (128 x 64)
__global__ __launch_bounds__(256) void k_gemm1(const float* __restrict__ X,
                                               const float* __restrict__ W1,
                                               float* __restrict__ xw, int N) {
    __shared__ __align__(16) float Ws[128 * 64];
    __shared__ __align__(16) float Xs[32][129];
    int tid = threadIdx.x;
    int m0 = blockIdx.x * 32;
    const float4* W4 = (const float4*)W1;
    float4* Ws4 = (float4*)Ws;
#pragma unroll
    for (int i = 0; i < 8; i++) Ws4[tid + i * 256] = W4[tid + i * 256];
#pragma unroll
    for (int i = 0; i < 4; i++) {
        int idx = tid + i * 256;
        int r = idx >> 5;
        int c = idx & 31;
        float4 v = ((const float4*)(X + (size_t)(m0 + r) * 128))[c];
        Xs[r][c * 4 + 0] = v.x; Xs[r][c * 4 + 1] = v.y;
        Xs[r][c * 4 + 2] = v.z; Xs[r][c * 4 + 3] = v.w;
    }
    __syncthreads();
    int r = tid & 31;
    int c0 = (tid >> 5) * 8;
    float acc[8] = {0, 0, 0, 0, 0, 0, 0, 0};
#pragma unroll 4
    for (int k = 0; k < 128; k++) {
        float xv = Xs[r][k];
        const float4* wr = (const float4*)&Ws[k * 64 + c0];
        float4 w0 = wr[0], w1 = wr[1];
        acc[0] += xv * w0.x; acc[1] += xv * w0.y; acc[2] += xv * w0.z; acc[3] += xv * w0.w;
        acc[4] += xv * w1.x; acc[5] += xv * w1.y; acc[6] += xv * w1.z; acc[7] += xv * w1.w;
    }
    float* out = xw + (size_t)(m0 + r) * 64 + c0;
    ((float4*)out)[0] = make_float4(acc[0], acc[1], acc[2], acc[3]);
    ((float4*)out)[1] = make_float4(acc[4], acc[5], acc[6], acc[7]);
}

// x[n] = dis[n] * sum_{e in CSR(n)} (ew*dis[src]) * xw[src]   — no atomics
__global__ __launch_bounds__(256) void k_gcn_agg(const int* __restrict__ off,
                                                 const unsigned long long* __restrict__ epk,
                                                 const float* __restrict__ dis,
                                                 const float* __restrict__ xw,
                                                 float* __restrict__ x, int N) {
    int lane = threadIdx.x & 63;
    int wv = threadIdx.x >> 6;
    int gw = blockIdx.x * 4 + wv;
    int stride = gridDim.x * 4;
    for (int n = gw; n < N; n += stride) {
        int b = off[n], en = off[n + 1];
        float acc = 0.f;
        for (int c = b; c < en; c += 64) {
            int idx = c + lane;
            int s = 0; float nw = 0.f;
            if (idx < en) {
                unsigned long long pk = epk[idx];
                s = (int)(unsigned)pk;
                nw = __uint_as_float((unsigned)(pk >> 32)) * dis[s];
            }
            int cc = min(64, en - c);
            for (int i = 0; i < cc; i++) {
                int ss = __shfl(s, i);
                float nn = __shfl(nw, i);
                acc += nn * xw[(size_t)ss * 64 + lane];
            }
        }
        x[(size_t)n * 64 + lane] = acc * dis[n];
    }
}

// g = relu(x + b1) @ W2   (N x 64) @ (64 x 192)
__global__ __launch_bounds__(256) void k_gemm2(const float* __restrict__ x,
                                               const float* __restrict__ W2,
                                               const float* __restrict__ b1,
                                               float* __restrict__ g, int N) {
    __shared__ __align__(16) float Ws[64 * 192];
    __shared__ __align__(16) float Xs[32][65];
    __shared__ float b1s[64];
    int tid = threadIdx.x;
    int m0 = blockIdx.x * 32;
    if (tid < 64) b1s[tid] = b1[tid];
    __syncthreads();
    const float4* W4 = (const float4*)W2;
    float4* Ws4 = (float4*)Ws;
#pragma unroll
    for (int i = 0; i < 12; i++) Ws4[tid + i * 256] = W4[tid + i * 256];
#pragma unroll
    for (int i = 0; i < 2; i++) {
        int idx = tid + i * 256;
        int r = idx >> 4;
        int c4 = idx & 15;
        float4 v = ((const float4*)(x + (size_t)(m0 + r) * 64))[c4];
        v.x = fmaxf(v.x + b1s[c4 * 4 + 0], 0.f);
        v.y = fmaxf(v.y + b1s[c4 * 4 + 1], 0.f);
        v.z = fmaxf(v.z + b1s[c4 * 4 + 2], 0.f);
        v.w = fmaxf(v.w + b1s[c4 * 4 + 3], 0.f);
        Xs[r][c4 * 4 + 0] = v.x; Xs[r][c4 * 4 + 1] = v.y;
        Xs[r][c4 * 4 + 2] = v.z; Xs[r][c4 * 4 + 3] = v.w;
    }
    __syncthreads();
    int r = tid & 31;
    int c0 = (tid >> 5) * 24;
    float acc[24];
#pragma unroll
    for (int j = 0; j < 24; j++) acc[j] = 0.f;
#pragma unroll 4
    for (int k = 0; k < 64; k++) {
        float xv = Xs[r][k];
        const float4* wr = (const float4*)&Ws[k * 192 + c0];
#pragma unroll
        for (int q = 0; q < 6; q++) {
            float4 wv = wr[q];
            acc[q * 4 + 0] += xv * wv.x;
            acc[q * 4 + 1] += xv * wv.y;
            acc[q * 4 + 2] += xv * wv.z;
            acc[q * 4 + 3] += xv * wv.w;
        }
    }
    float* out = g + (size_t)(m0 + r) * 192 + c0;
#pragma unroll
    for (int q = 0; q < 6; q++)
        ((float4*)out)[q] = make_float4(acc[q * 4 + 0], acc[q * 4 + 1], acc[q * 4 + 2], acc[q * 4 + 3]);
}

// a_src[n,h] = <g[n,h,:], att_src[h,:]> ; a_dst likewise
__global__ __launch_bounds__(256) void k_att(const float* __restrict__ g,
                                             const float* __restrict__ att_src,
                                             const float* __restrict__ att_dst,
                                             float* __restrict__ asrc,
                                             float* __restrict__ adst, int N3) {
    __shared__ float as_s[192], ad_s[192];
    int tid = threadIdx.x;
    if (tid < 192) { as_s[tid] = att_src[tid]; ad_s[tid] = att_dst[tid]; }
    __syncthreads();
    int idx = blockIdx.x * 256 + tid;
    if (idx < N3) {
        int n = idx / 3, h = idx - 3 * n;
        const float4* gr = (const float4*)(g + (size_t)n * 192 + h * 64);
        const float4* av = (const float4*)(as_s + h * 64);
        const float4* bv = (const float4*)(ad_s + h * 64);
        float sa = 0.f, sb = 0.f;
#pragma unroll
        for (int i = 0; i < 16; i++) {
            float4 gv = gr[i]; float4 a = av[i]; float4 b = bv[i];
            sa += gv.x * a.x + gv.y * a.y + gv.z * a.z + gv.w * a.w;
            sb += gv.x * b.x + gv.y * b.y + gv.z * b.z + gv.w * b.w;
        }
        asrc[idx] = sa; adst[idx] = sb;
    }
}

// fused GAT: per (node, head) wave, online softmax over CSR edges, accumulate
// sum_e attn*g[src] into per-wave running total, one atomicAdd per wave.
// gridDim.x*4 must be divisible by 3.
__global__ __launch_bounds__(256) void k_gat(const int* __restrict__ off,
                                             const unsigned long long* __restrict__ epk,
                                             const float* __restrict__ asrc,
                                             const float* __restrict__ adst,
                                             const float* __restrict__ g,
                                             float* __restrict__ gsum, int N) {
    int lane = threadIdx.x & 63;
    int wv = threadIdx.x >> 6;
    int gw = blockIdx.x * 4 + wv;
    int h = gw % 3;
    int hoff = h * 64;
    int nstride = (gridDim.x * 4) / 3;
    float tot = 0.f;
    for (int n = gw / 3; n < N; n += nstride) {
        int b = off[n], en = off[n + 1];
        float adn = adst[(size_t)n * 3 + h];
        float m = -INFINITY, sum = 0.f, accv = 0.f;
        for (int c = b; c < en; c += 64) {
            int idx = c + lane;
            int s = 0; float al = -INFINITY;
            if (idx < en) {
                s = (int)(unsigned)epk[idx];
                al = lrelu(asrc[s * 3 + h] + adn);
            }
            float cm = wave_max(al);
            if (cm > m) {
                float r = __expf(m - cm);
                accv *= r; sum *= r; m = cm;
            }
            float ex = __expf(al - m);
            int cc = min(64, en - c);
            for (int i = 0; i < cc; i++) {
                float exi = __shfl(ex, i);
                int ss = __shfl(s, i);
                sum += exi;
                accv += exi * g[(size_t)ss * 192 + hoff + lane];
            }
        }
        tot += accv / (sum + 1e-16f);
    }
    atomicAdd(&gsum[hoff + lane], tot);
}

// out = gsum/N + b2
__global__ void k_final(const float* __restrict__ gsum, const float* __restrict__ b2,
                        float* __restrict__ out, float invN) {
    int j = threadIdx.x;
    if (j < 192) out[j] = gsum[j] * invN + b2[j];
}

// ---------- launcher ----------
extern "C" void kernel_launch(void* const* d_in, const int* in_sizes, int n_in,
                              void* d_out, int out_size, void* d_ws, size_t ws_size,
                              hipStream_t stream) {
    const float* X   = (const float*)d_in[0];
    const int*   ei  = (const int*)d_in[1];
    const float* ew  = (const float*)d_in[2];
    const float* W1  = (const float*)d_in[3];
    const float* b1  = (const float*)d_in[4];
    const float* W2  = (const float*)d_in[5];
    const float* b2  = (const float*)d_in[6];
    const float* ats = (const float*)d_in[7];
    const float* atd = (const float*)d_in[8];

    int N  = in_sizes[0] / 128;
    int E  = in_sizes[1] / 2;
    int Et = E + N;
    const int* srcI = ei;
    const int* dstI = ei + E;

    float* ws = (float*)d_ws;
    int*   wsi = (int*)d_ws;

    // layout (4B units)
    size_t o = 0;
    int* off_p = wsi + o;           o += (size_t)N + 1;
    int* cur_p = wsi + o;           o += (size_t)N + 1;
    int* cnt_p = wsi + o;           size_t z0 = o; o += (size_t)N;   // zeroed
    float* gsum = ws + o;           o += 192;                        // zeroed
    size_t z1 = o;
    int* part_p = wsi + o;          o += 256;
    float* dis  = ws + o;           o += (size_t)N;
    float* asrc = ws + o;           o += (size_t)N * 3;
    float* adst = ws + o;           o += (size_t)N * 3;
    float* xw   = ws + o;           o += (size_t)N * 64;
    float* x    = ws + o;           o += (size_t)N * 64;
    float* g    = ws + o;           o += (size_t)N * 192;
    o = (o + 1) & ~(size_t)1;       // 8B align
    unsigned long long* epk = (unsigned long long*)(ws + o);

    // zero cnt + gsum in one memset
    hipMemsetAsync(wsi + z0, 0, (z1 - z0) * sizeof(int), stream);

    int nb = (N + 1023) / 1024;     // scan blocks (<=256)

    k_hist <<<(E + 255) / 256, 256, 0, stream>>>(dstI, cnt_p, E);
    k_scan1<<<nb, 256, 0, stream>>>(cnt_p, off_p, part_p, N);
    k_scan2<<<1, 256, 0, stream>>>(part_p, nb);
    k_scan3<<<nb, 256, 0, stream>>>(off_p, cur_p, part_p, N, Et);
    k_fill <<<(Et + 255) / 256, 256, 0, stream>>>(srcI, dstI, ew, cur_p, epk, E, Et);
    k_degdis<<<(N + 255) / 256, 256, 0, stream>>>(off_p, epk, dis, N);
    k_gemm1<<<N / 32, 256, 0, stream>>>(X, W1, xw, N);
    k_gcn_agg<<<2048, 256, 0, stream>>>(off_p, epk, dis, xw, x, N);
    k_gemm2<<<N / 32, 256, 0, stream>>>(x, W2, b1, g, N);
    k_att<<<(3 * N + 255) / 256, 256, 0, stream>>>(g, ats, atd, asrc, adst, 3 * N);
    k_gat<<<1536, 256, 0, stream>>>(off_p, epk, asrc, adst, g, gsum, N);  // 6144 waves, %3==0
    k_final<<<1, 192, 0, stream>>>(gsum, b2, (float*)d_out, 1.0f / (float)N);
}

// Round 3
// 784.929 us; speedup vs baseline: 1.8016x; 1.1548x over previous
//
#include <hip/hip_runtime.h>
#include <math.h>

__device__ __forceinline__ float lrelu(float v) { return v > 0.f ? v : 0.2f * v; }

// merge per-lane online-softmax states (m, s) across the wave; all lanes converge
__device__ __forceinline__ void sm_merge(float& m, float& s) {
#pragma unroll
    for (int o = 1; o < 64; o <<= 1) {
        float mo = __shfl_xor(m, o);
        float so = __shfl_xor(s, o);
        float nm = fmaxf(m, mo);
        s = s * __expf(m - nm) + so * __expf(mo - nm);
        m = nm;
    }
}

// ---------- CSR build ----------

__global__ void k_hist(const int* __restrict__ dst, int* __restrict__ cnt, int E) {
    int e = blockIdx.x * 256 + threadIdx.x;
    if (e < E) atomicAdd(&cnt[dst[e]], 1);
}

// block-local exclusive scan of (cnt[n]+1), 1024 elems/block
__global__ __launch_bounds__(256) void k_scan1(const int* __restrict__ cnt,
                                               int* __restrict__ off,
                                               int* __restrict__ partials, int N) {
    __shared__ int sh[256];
    int tid = threadIdx.x;
    int base = blockIdx.x * 1024 + tid * 4;
    int v[4]; int tsum = 0;
#pragma unroll
    for (int i = 0; i < 4; i++) {
        int n = base + i;
        int c = (n < N) ? cnt[n] + 1 : 0;
        v[i] = tsum; tsum += c;
    }
    sh[tid] = tsum; __syncthreads();
    int mine = tsum;
    for (int o = 1; o < 256; o <<= 1) {
        int t = (tid >= o) ? sh[tid - o] : 0;
        __syncthreads();
        sh[tid] += t;
        __syncthreads();
    }
    int excl = sh[tid] - mine;
#pragma unroll
    for (int i = 0; i < 4; i++) {
        int n = base + i;
        if (n < N) off[n] = excl + v[i];
    }
    if (tid == 255) partials[blockIdx.x] = sh[255];
}

__global__ void k_scan2(int* __restrict__ partials, int nb) {
    __shared__ int sh[256];
    int tid = threadIdx.x;
    int v = (tid < nb) ? partials[tid] : 0;
    sh[tid] = v; __syncthreads();
    for (int o = 1; o < 256; o <<= 1) {
        int t = (tid >= o) ? sh[tid - o] : 0;
        __syncthreads();
        sh[tid] += t;
        __syncthreads();
    }
    if (tid < nb) partials[tid] = sh[tid] - v;
}

__global__ void k_scan3(int* __restrict__ off, int* __restrict__ cursor,
                        const int* __restrict__ partials, int N, int Et) {
    int base = blockIdx.x * 1024 + threadIdx.x * 4;
    int add = partials[blockIdx.x];
#pragma unroll
    for (int i = 0; i < 4; i++) {
        int n = base + i;
        if (n < N) { int o = off[n] + add; off[n] = o; cursor[n] = o; }
    }
    if (blockIdx.x == 0 && threadIdx.x == 0) { off[N] = Et; cursor[N] = Et; }
}

__global__ void k_fill(const int* __restrict__ src, const int* __restrict__ dst,
                       const float* __restrict__ ew, int* __restrict__ cursor,
                       unsigned long long* __restrict__ epk, int E, int Et) {
    int e = blockIdx.x * 256 + threadIdx.x;
    if (e >= Et) return;
    int s, d; float w;
    if (e < E) { s = src[e]; d = dst[e]; w = ew[e]; }
    else       { s = d = e - E; w = 1.0f; }
    int p = atomicAdd(&cursor[d], 1);
    epk[p] = ((unsigned long long)__float_as_uint(w) << 32) | (unsigned)s;
}

__global__ void k_degdis(const int* __restrict__ off,
                         const unsigned long long* __restrict__ epk,
                         float* __restrict__ dis, int N) {
    int n = blockIdx.x * 256 + threadIdx.x;
    if (n >= N) return;
    int b = off[n], e2 = off[n + 1];
    float s = 0.f;
    for (int i = b; i < e2; i++) s += __uint_as_float((unsigned)(epk[i] >> 32));
    dis[n] = rsqrtf(s);
}

// ---------- dense kernels ----------

// xw = X @ W1   (N x 128) @ (128 x 64)
__global__ __launch_bounds__(256) void k_gemm1(const float* __restrict__ X,
                                               const float* __restrict__ W1,
                                               float* __restrict__ xw, int N) {
    __shared__ __align__(16) float Ws[128 * 64];
    __shared__ __align__(16) float Xs[32][129];
    int tid = threadIdx.x;
    int m0 = blockIdx.x * 32;
    const float4* W4 = (const float4*)W1;
    float4* Ws4 = (float4*)Ws;
#pragma unroll
    for (int i = 0; i < 8; i++) Ws4[tid + i * 256] = W4[tid + i * 256];
#pragma unroll
    for (int i = 0; i < 4; i++) {
        int idx = tid + i * 256;
        int r = idx >> 5;
        int c = idx & 31;
        float4 v = ((const float4*)(X + (size_t)(m0 + r) * 128))[c];
        Xs[r][c * 4 + 0] = v.x; Xs[r][c * 4 + 1] = v.y;
        Xs[r][c * 4 + 2] = v.z; Xs[r][c * 4 + 3] = v.w;
    }
    __syncthreads();
    int r = tid & 31;
    int c0 = (tid >> 5) * 8;
    float acc[8] = {0, 0, 0, 0, 0, 0, 0, 0};
#pragma unroll 4
    for (int k = 0; k < 128; k++) {
        float xv = Xs[r][k];
        const float4* wr = (const float4*)&Ws[k * 64 + c0];
        float4 w0 = wr[0], w1 = wr[1];
        acc[0] += xv * w0.x; acc[1] += xv * w0.y; acc[2] += xv * w0.z; acc[3] += xv * w0.w;
        acc[4] += xv * w1.x; acc[5] += xv * w1.y; acc[6] += xv * w1.z; acc[7] += xv * w1.w;
    }
    float* out = xw + (size_t)(m0 + r) * 64 + c0;
    ((float4*)out)[0] = make_float4(acc[0], acc[1], acc[2], acc[3]);
    ((float4*)out)[1] = make_float4(acc[4], acc[5], acc[6], acc[7]);
}

// x[n] = dis[n] * sum_{e in CSR(n)} (ew*dis[src]) * xw[src]
// 4 edge-slots x 16 lanes (float4 features) for 4x memory-level parallelism
__global__ __launch_bounds__(256) void k_gcn_agg(const int* __restrict__ off,
                                                 const unsigned long long* __restrict__ epk,
                                                 const float* __restrict__ dis,
                                                 const float* __restrict__ xw,
                                                 float* __restrict__ x, int N) {
    int lane = threadIdx.x & 63;
    int wv = threadIdx.x >> 6;
    int slot = lane >> 4;   // 0..3
    int f4 = lane & 15;     // float4 index 0..15
    int gw = blockIdx.x * 4 + wv;
    int stride = gridDim.x * 4;
    for (int n = gw; n < N; n += stride) {
        int b = off[n], en = off[n + 1];
        float4 acc = make_float4(0.f, 0.f, 0.f, 0.f);
        for (int c = b; c < en; c += 64) {
            int idx = c + lane;
            int s = 0; float nw = 0.f;
            if (idx < en) {
                unsigned long long pk = epk[idx];
                s = (int)(unsigned)pk;
                nw = __uint_as_float((unsigned)(pk >> 32)) * dis[s];
            }
            int cc = min(64, en - c);
            for (int i = 0; i * 4 < cc; i++) {
                int eo = i * 4 + slot;
                int ss = __shfl(s, eo);
                float nn = __shfl(nw, eo);
                if (eo < cc) {
                    float4 v = ((const float4*)(xw + (size_t)ss * 64))[f4];
                    acc.x += nn * v.x; acc.y += nn * v.y;
                    acc.z += nn * v.z; acc.w += nn * v.w;
                }
            }
        }
        acc.x += __shfl_xor(acc.x, 16); acc.y += __shfl_xor(acc.y, 16);
        acc.z += __shfl_xor(acc.z, 16); acc.w += __shfl_xor(acc.w, 16);
        acc.x += __shfl_xor(acc.x, 32); acc.y += __shfl_xor(acc.y, 32);
        acc.z += __shfl_xor(acc.z, 32); acc.w += __shfl_xor(acc.w, 32);
        if (lane < 16) {
            float dn = dis[n];
            ((float4*)(x + (size_t)n * 64))[f4] =
                make_float4(acc.x * dn, acc.y * dn, acc.z * dn, acc.w * dn);
        }
    }
}

// g = relu(x + b1) @ W2   (N x 64) @ (64 x 192)
__global__ __launch_bounds__(256) void k_gemm2(const float* __restrict__ x,
                                               const float* __restrict__ W2,
                                               const float* __restrict__ b1,
                                               float* __restrict__ g, int N) {
    __shared__ __align__(16) float Ws[64 * 192];
    __shared__ __align__(16) float Xs[32][65];
    __shared__ float b1s[64];
    int tid = threadIdx.x;
    int m0 = blockIdx.x * 32;
    if (tid < 64) b1s[tid] = b1[tid];
    __syncthreads();
    const float4* W4 = (const float4*)W2;
    float4* Ws4 = (float4*)Ws;
#pragma unroll
    for (int i = 0; i < 12; i++) Ws4[tid + i * 256] = W4[tid + i * 256];
#pragma unroll
    for (int i = 0; i < 2; i++) {
        int idx = tid + i * 256;
        int r = idx >> 4;
        int c4 = idx & 15;
        float4 v = ((const float4*)(x + (size_t)(m0 + r) * 64))[c4];
        v.x = fmaxf(v.x + b1s[c4 * 4 + 0], 0.f);
        v.y = fmaxf(v.y + b1s[c4 * 4 + 1], 0.f);
        v.z = fmaxf(v.z + b1s[c4 * 4 + 2], 0.f);
        v.w = fmaxf(v.w + b1s[c4 * 4 + 3], 0.f);
        Xs[r][c4 * 4 + 0] = v.x; Xs[r][c4 * 4 + 1] = v.y;
        Xs[r][c4 * 4 + 2] = v.z; Xs[r][c4 * 4 + 3] = v.w;
    }
    __syncthreads();
    int r = tid & 31;
    int c0 = (tid >> 5) * 24;
    float acc[24];
#pragma unroll
    for (int j = 0; j < 24; j++) acc[j] = 0.f;
#pragma unroll 4
    for (int k = 0; k < 64; k++) {
        float xv = Xs[r][k];
        const float4* wr = (const float4*)&Ws[k * 192 + c0];
#pragma unroll
        for (int q = 0; q < 6; q++) {
            float4 wv = wr[q];
            acc[q * 4 + 0] += xv * wv.x;
            acc[q * 4 + 1] += xv * wv.y;
            acc[q * 4 + 2] += xv * wv.z;
            acc[q * 4 + 3] += xv * wv.w;
        }
    }
    float* out = g + (size_t)(m0 + r) * 192 + c0;
#pragma unroll
    for (int q = 0; q < 6; q++)
        ((float4*)out)[q] = make_float4(acc[q * 4 + 0], acc[q * 4 + 1], acc[q * 4 + 2], acc[q * 4 + 3]);
}

// asrc4[n*4+h] = <g[n,h,:], att_src[h,:]> ; adst[n*3+h] likewise
__global__ __launch_bounds__(256) void k_att(const float* __restrict__ g,
                                             const float* __restrict__ att_src,
                                             const float* __restrict__ att_dst,
                                             float* __restrict__ asrc4,
                                             float* __restrict__ adst, int N3) {
    __shared__ float as_s[192], ad_s[192];
    int tid = threadIdx.x;
    if (tid < 192) { as_s[tid] = att_src[tid]; ad_s[tid] = att_dst[tid]; }
    __syncthreads();
    int idx = blockIdx.x * 256 + tid;
    if (idx < N3) {
        int n = idx / 3, h = idx - 3 * n;
        const float4* gr = (const float4*)(g + (size_t)n * 192 + h * 64);
        const float4* av = (const float4*)(as_s + h * 64);
        const float4* bv = (const float4*)(ad_s + h * 64);
        float sa = 0.f, sb = 0.f;
#pragma unroll
        for (int i = 0; i < 16; i++) {
            float4 gv = gr[i]; float4 a = av[i]; float4 b = bv[i];
            sa += gv.x * a.x + gv.y * a.y + gv.z * a.z + gv.w * a.w;
            sb += gv.x * b.x + gv.y * b.y + gv.z * b.z + gv.w * b.w;
        }
        asrc4[(size_t)n * 4 + h] = sa;
        adst[idx] = sb;
    }
}

// per dst-node wave: online softmax (3 heads, registers only), then scatter
// per-edge attention scalars into w[src,h]
__global__ __launch_bounds__(256) void k_gatsm(const int* __restrict__ off,
                                               const unsigned long long* __restrict__ epk,
                                               const float* __restrict__ asrc4,
                                               const float* __restrict__ adst,
                                               float* __restrict__ w, int N) {
    int lane = threadIdx.x & 63;
    int wv = threadIdx.x >> 6;
    int gw = blockIdx.x * 4 + wv;
    int stride = gridDim.x * 4;
    for (int n = gw; n < N; n += stride) {
        int b = off[n], en = off[n + 1];
        float ad0 = adst[(size_t)n * 3 + 0];
        float ad1 = adst[(size_t)n * 3 + 1];
        float ad2 = adst[(size_t)n * 3 + 2];
        float m0 = -1e30f, m1 = -1e30f, m2 = -1e30f;
        float s0 = 0.f, s1 = 0.f, s2 = 0.f;
        for (int idx = b + lane; idx < en; idx += 64) {
            int s = (int)(unsigned)epk[idx];
            float4 av = ((const float4*)asrc4)[s];
            float a0 = lrelu(av.x + ad0);
            float a1 = lrelu(av.y + ad1);
            float a2 = lrelu(av.z + ad2);
            float nm;
            nm = fmaxf(m0, a0); s0 = s0 * __expf(m0 - nm) + __expf(a0 - nm); m0 = nm;
            nm = fmaxf(m1, a1); s1 = s1 * __expf(m1 - nm) + __expf(a1 - nm); m1 = nm;
            nm = fmaxf(m2, a2); s2 = s2 * __expf(m2 - nm) + __expf(a2 - nm); m2 = nm;
        }
        sm_merge(m0, s0); sm_merge(m1, s1); sm_merge(m2, s2);
        float i0 = 1.f / (s0 + 1e-16f);
        float i1 = 1.f / (s1 + 1e-16f);
        float i2 = 1.f / (s2 + 1e-16f);
        for (int idx = b + lane; idx < en; idx += 64) {
            int s = (int)(unsigned)epk[idx];
            float4 av = ((const float4*)asrc4)[s];
            atomicAdd(&w[(size_t)s * 3 + 0], __expf(lrelu(av.x + ad0) - m0) * i0);
            atomicAdd(&w[(size_t)s * 3 + 1], __expf(lrelu(av.y + ad1) - m1) * i1);
            atomicAdd(&w[(size_t)s * 3 + 2], __expf(lrelu(av.z + ad2) - m2) * i2);
        }
    }
}

// gsum[j] = sum_n w[n, j/64] * g[n*192+j]   (dense, coalesced)
__global__ __launch_bounds__(192) void k_wsum(const float* __restrict__ w,
                                              const float* __restrict__ g,
                                              float* __restrict__ gsum, int N) {
    int j = threadIdx.x;
    int h = j >> 6;
    int gs = gridDim.x;
    float a0 = 0.f, a1 = 0.f;
    int n = blockIdx.x;
    for (; n + gs < N; n += 2 * gs) {
        a0 += w[(size_t)n * 3 + h] * g[(size_t)n * 192 + j];
        a1 += w[(size_t)(n + gs) * 3 + h] * g[(size_t)(n + gs) * 192 + j];
    }
    if (n < N) a0 += w[(size_t)n * 3 + h] * g[(size_t)n * 192 + j];
    atomicAdd(&gsum[j], a0 + a1);
}

__global__ void k_final(const float* __restrict__ gsum, const float* __restrict__ b2,
                        float* __restrict__ out, float invN) {
    int j = threadIdx.x;
    if (j < 192) out[j] = gsum[j] * invN + b2[j];
}

// ---------- launcher ----------
extern "C" void kernel_launch(void* const* d_in, const int* in_sizes, int n_in,
                              void* d_out, int out_size, void* d_ws, size_t ws_size,
                              hipStream_t stream) {
    const float* X   = (const float*)d_in[0];
    const int*   ei  = (const int*)d_in[1];
    const float* ew  = (const float*)d_in[2];
    const float* W1  = (const float*)d_in[3];
    const float* b1  = (const float*)d_in[4];
    const float* W2  = (const float*)d_in[5];
    const float* b2  = (const float*)d_in[6];
    const float* ats = (const float*)d_in[7];
    const float* atd = (const float*)d_in[8];

    int N  = in_sizes[0] / 128;
    int E  = in_sizes[1] / 2;
    int Et = E + N;
    const int* srcI = ei;
    const int* dstI = ei + E;

    float* ws = (float*)d_ws;
    int*   wsi = (int*)d_ws;

    size_t o = 0;
    int* off_p = wsi + o;           o += (size_t)N + 1;
    int* cur_p = wsi + o;           o += (size_t)N + 1;
    size_t z0 = o;
    int* cnt_p = wsi + o;           o += (size_t)N;        // zeroed
    float* w_p = ws + o;            o += (size_t)N * 3;    // zeroed
    float* gsum = ws + o;           o += 192;              // zeroed
    size_t z1 = o;
    int* part_p = wsi + o;          o += 256;
    float* dis  = ws + o;           o += (size_t)N;
    o = (o + 3) & ~(size_t)3;                              // 16B align
    float* asrc4 = ws + o;          o += (size_t)N * 4;
    float* adst  = ws + o;          o += (size_t)N * 3;
    float* xw   = ws + o;           o += (size_t)N * 64;
    float* x    = ws + o;           o += (size_t)N * 64;
    float* g    = ws + o;           o += (size_t)N * 192;
    o = (o + 1) & ~(size_t)1;                              // 8B align
    unsigned long long* epk = (unsigned long long*)(ws + o);

    hipMemsetAsync(wsi + z0, 0, (z1 - z0) * sizeof(int), stream);

    int nb = (N + 1023) / 1024;

    k_hist <<<(E + 255) / 256, 256, 0, stream>>>(dstI, cnt_p, E);
    k_scan1<<<nb, 256, 0, stream>>>(cnt_p, off_p, part_p, N);
    k_scan2<<<1, 256, 0, stream>>>(part_p, nb);
    k_scan3<<<nb, 256, 0, stream>>>(off_p, cur_p, part_p, N, Et);
    k_fill <<<(Et + 255) / 256, 256, 0, stream>>>(srcI, dstI, ew, cur_p, epk, E, Et);
    k_degdis<<<(N + 255) / 256, 256, 0, stream>>>(off_p, epk, dis, N);
    k_gemm1<<<N / 32, 256, 0, stream>>>(X, W1, xw, N);
    k_gcn_agg<<<2048, 256, 0, stream>>>(off_p, epk, dis, xw, x, N);
    k_gemm2<<<N / 32, 256, 0, stream>>>(x, W2, b1, g, N);
    k_att<<<(3 * N + 255) / 256, 256, 0, stream>>>(g, ats, atd, asrc4, adst, 3 * N);
    k_gatsm<<<2048, 256, 0, stream>>>(off_p, epk, asrc4, adst, w_p, N);
    k_wsum<<<512, 192, 0, stream>>>(w_p, g, gsum, N);
    k_final<<<1, 192, 0, stream>>>(gsum, b2, (float*)d_out, 1.0f / (float)N);
}